// Round 2
// baseline (101.047 us; speedup 1.0000x reference)
//
#include <hip/hip_runtime.h>

// Problem constants
#define NB   8192
#define ND   256
#define NH1  50
#define NH2  32
#define NH3  18
#define RPB  16              // rows per block
#define TPB  128             // threads per block (2 waves)
#define NBLK (NB / RPB)      // 512 blocks
#define WSS  40              // per-block ws slot stride (floats)

// ws layout: ws[b*WSS + c], c: [0..17] ysum part, [18..35] colsum(W_user) part,
//            [36] sum(log_denom) part. No atomics, no zero-init needed.

__device__ __forceinline__ float sigmoidf_fast(float v) {
    return 1.0f / (1.0f + __expf(-v));
}

// DPP-based 16-lane-group sum: VALU pipe only (no LDS/ds_bpermute).
template <int CTRL>
__device__ __forceinline__ float dpp_addf(float v) {
    return v + __int_as_float(__builtin_amdgcn_update_dpp(
        0, __float_as_int(v), CTRL, 0xF, 0xF, true));
}
__device__ __forceinline__ float sum16(float v) {
    v = dpp_addf<0xB1>(v);    // quad_perm xor 1
    v = dpp_addf<0x4E>(v);    // quad_perm xor 2
    v = dpp_addf<0x124>(v);   // row_ror:4
    v = dpp_addf<0x128>(v);   // row_ror:8
    return v;
}

// async global->LDS, 16B per lane, wave-uniform LDS base + lane*16
__device__ __forceinline__ void gload_lds16(const float* g, float* l) {
    __builtin_amdgcn_global_load_lds(
        (const __attribute__((address_space(1))) unsigned int*)g,
        (__attribute__((address_space(3))) unsigned int*)l, 16, 0, 0);
}

// R=2 register reuse: each lane computes TWO rows (rs, rs+8) so every W1
// value read from LDS feeds 2 FMAs -> per-CU LDS traffic halves vs R=1.
__global__ __launch_bounds__(TPB) void fused_main(
    const float* __restrict__ x, const float* __restrict__ y,
    const float* __restrict__ W1, const float* __restrict__ b1,
    const float* __restrict__ W2, const float* __restrict__ b2,
    const float* __restrict__ W3, const float* __restrict__ b3,
    float* __restrict__ out, float* __restrict__ ws)
{
    __shared__ alignas(16) float w1l[ND * NH1];     // 51200 B, row-major [k][j]
    __shared__ alignas(16) float w2l[NH1 * NH2];    // 6400 B
    __shared__ alignas(16) float w3l[NH2 * NH3];    // 2304 B
    __shared__ alignas(16) float h2l[RPB][NH2 + 2]; // stride 34
    __shared__ alignas(16) float wul[RPB][NH3 + 1]; // stride 19
    // total 63296 B -> 2 blocks/CU

    const int t    = threadIdx.x;
    const int rs   = t >> 4;          // 0..7 row slot
    const int ksl  = t & 15;          // k-slice within row
    const int lane = t & 63;
    const int wave = t >> 6;          // 0..1
    const int g0   = blockIdx.x * RPB + rs;       // row A
    const int g1   = g0 + 8;                      // row B

    // ---- issue x loads for both rows first (stay in flight over staging) ----
    const float* xr0 = x + (size_t)g0 * ND + 2 * ksl;
    const float* xr1 = x + (size_t)g1 * ND + 2 * ksl;
    float2 xv0[8], xv1[8];
#pragma unroll
    for (int c = 0; c < 8; ++c) {
        xv0[c] = *reinterpret_cast<const float2*>(xr0 + 32 * c);
        xv1[c] = *reinterpret_cast<const float2*>(xr1 + 32 * c);
    }

    // ---- stage W1 row-major via global_load_lds: 50 chunks of 1024 B ----
#pragma unroll
    for (int i = 0; i < 25; ++i) {
        const int c = wave + 2 * i;               // wave-uniform chunk id, 0..49
        gload_lds16(W1 + c * 256 + lane * 4, w1l + c * 256);
    }
    for (int e = t; e < NH1 * NH2; e += TPB) w2l[e] = W2[e];
    for (int e = t; e < NH2 * NH3; e += TPB) w3l[e] = W3[e];
    __syncthreads();

    // ---- layer 1: rows kA=32c+2ksl, kA+1 are 100 CONTIGUOUS 16B-aligned
    //      floats in w1l -> pure ds_read_b128, each feeding both rows ----
    float h1a[NH1], h1b[NH1];
#pragma unroll
    for (int j = 0; j < NH1; ++j) { h1a[j] = 0.0f; h1b[j] = 0.0f; }
#pragma unroll
    for (int c = 0; c < 8; ++c) {
        const int kA = 32 * c + 2 * ksl;
        const float* wp = &w1l[kA * NH1];
        const float xa0 = xv0[c].x, xb0 = xv0[c].y;   // row A: x[kA], x[kA+1]
        const float xa1 = xv1[c].x, xb1 = xv1[c].y;   // row B
#pragma unroll
        for (int q = 0; q < 25; ++q) {
            const float4 w = *reinterpret_cast<const float4*>(wp + 4 * q);
            const float we[4] = {w.x, w.y, w.z, w.w};
#pragma unroll
            for (int s = 0; s < 4; ++s) {
                const int e = 4 * q + s;              // compile-time after unroll
                if (e < NH1) {
                    h1a[e] = fmaf(xa0, we[s], h1a[e]);
                    h1b[e] = fmaf(xa1, we[s], h1b[e]);
                } else {
                    h1a[e - NH1] = fmaf(xb0, we[s], h1a[e - NH1]);
                    h1b[e - NH1] = fmaf(xb1, we[s], h1b[e - NH1]);
                }
            }
        }
    }
    // 16-lane reduction on the VALU (DPP), bias + sigmoid
#pragma unroll
    for (int j = 0; j < NH1; ++j) {
        h1a[j] = sigmoidf_fast(sum16(h1a[j]) + b1[j]);
        h1b[j] = sigmoidf_fast(sum16(h1b[j]) + b1[j]);
    }

    // ---- layer 2: lane computes 2 cols x 2 rows ----
    {
        const float2 bb = *reinterpret_cast<const float2*>(b2 + 2 * ksl);
        float aa0 = bb.x, aa1 = bb.y, ba0 = bb.x, ba1 = bb.y;
#pragma unroll
        for (int j = 0; j < NH1; ++j) {
            const float2 w = *reinterpret_cast<const float2*>(&w2l[j * NH2 + 2 * ksl]);
            aa0 = fmaf(h1a[j], w.x, aa0);
            aa1 = fmaf(h1a[j], w.y, aa1);
            ba0 = fmaf(h1b[j], w.x, ba0);
            ba1 = fmaf(h1b[j], w.y, ba1);
        }
        *reinterpret_cast<float2*>(&h2l[rs][2 * ksl]) =
            make_float2(sigmoidf_fast(aa0), sigmoidf_fast(aa1));
        *reinterpret_cast<float2*>(&h2l[rs + 8][2 * ksl]) =
            make_float2(sigmoidf_fast(ba0), sigmoidf_fast(ba1));
    }
    // NO barrier: layer 3 reads only h2l rows written by this lane's own
    // 16-lane group (same wave, lockstep; compiler orders via lgkmcnt).

    // ---- layer 3: lane computes col ksl (and 16+ksl for ksl<2), 2 rows ----
    {
        float a0A = b3[ksl], a0B = b3[ksl];
        float a1A = (ksl < 2) ? b3[16 + ksl] : 0.0f;
        float a1B = a1A;
#pragma unroll
        for (int j = 0; j < NH2; ++j) {
            const float hA = h2l[rs][j];              // broadcast within 16-group
            const float hB = h2l[rs + 8][j];
            const float w3v = w3l[j * NH3 + ksl];
            a0A = fmaf(hA, w3v, a0A);
            a0B = fmaf(hB, w3v, a0B);
            if (ksl < 2) {
                const float w3x = w3l[j * NH3 + 16 + ksl];
                a1A = fmaf(hA, w3x, a1A);
                a1B = fmaf(hB, w3x, a1B);
            }
        }
        wul[rs][ksl] = a0A;
        wul[rs + 8][ksl] = a0B;
        out[(size_t)g0 * NH3 + ksl] = a0A;
        out[(size_t)g1 * NH3 + ksl] = a0B;
        if (ksl < 2) {
            wul[rs][16 + ksl] = a1A;
            wul[rs + 8][16 + ksl] = a1B;
            out[(size_t)g0 * NH3 + 16 + ksl] = a1A;
            out[(size_t)g1 * NH3 + 16 + ksl] = a1B;
        }
    }
    __syncthreads();   // epilogue wave reads all 16 rows (cross-wave)

    // ---- epilogue on wave 0: factorized LSE + block reductions ----
    if (t < 64) {
        const bool act = t < RPB;
        float wv[NH3], yv[NH3];
        float ld = 0.0f;
        if (act) {
            const float* yrow = y + (size_t)(blockIdx.x * RPB + t) * NH3;
#pragma unroll
            for (int c = 0; c < NH3; ++c) {
                wv[c] = wul[t][c];
                yv[c] = yrow[c];
            }
            // factorized logsumexp over cartesian one-hot cases:
            // groups [0,2) [2,6) [6,10) [10,18)
            float m = fmaxf(wv[0], wv[1]);
            ld += m + __logf(__expf(wv[0] - m) + __expf(wv[1] - m));
            m = fmaxf(fmaxf(wv[2], wv[3]), fmaxf(wv[4], wv[5]));
            ld += m + __logf(__expf(wv[2] - m) + __expf(wv[3] - m) +
                             __expf(wv[4] - m) + __expf(wv[5] - m));
            m = fmaxf(fmaxf(wv[6], wv[7]), fmaxf(wv[8], wv[9]));
            ld += m + __logf(__expf(wv[6] - m) + __expf(wv[7] - m) +
                             __expf(wv[8] - m) + __expf(wv[9] - m));
            m = wv[10];
#pragma unroll
            for (int i = 11; i < NH3; ++i) m = fmaxf(m, wv[i]);
            float s = 0.0f;
#pragma unroll
            for (int i = 10; i < NH3; ++i) s += __expf(wv[i] - m);
            ld += m + __logf(s);
        } else {
#pragma unroll
            for (int c = 0; c < NH3; ++c) { wv[c] = 0.0f; yv[c] = 0.0f; }
        }

        // 16-lane DPP reductions; lanes 0..15 hold block totals
        ld = sum16(ld);
#pragma unroll
        for (int c = 0; c < NH3; ++c) {
            wv[c] = sum16(wv[c]);
            yv[c] = sum16(yv[c]);
        }
        if (t == 0) {
            float* slot = ws + (size_t)blockIdx.x * WSS;
#pragma unroll
            for (int c = 0; c < NH3; ++c) {
                slot[c]       = yv[c];       // ysum partial
                slot[NH3 + c] = wv[c];       // colsum(W_user) partial
            }
            slot[36] = ld;                   // log_denom partial
        }
    }
}

__global__ __launch_bounds__(256) void finalize_loss(
    const float* __restrict__ ws, float* __restrict__ out)
{
    __shared__ double part[4][37];
    const int t = threadIdx.x;
    const int w = t >> 6, l = t & 63;
    if (l < 37) {
        double a = 0.0;
        for (int b = w * (NBLK / 4); b < (w + 1) * (NBLK / 4); ++b)
            a += (double)ws[(size_t)b * WSS + l];   // lanes 0..36 coalesced
        part[w][l] = a;
    }
    __syncthreads();
    if (t == 0) {
        double tot[37];
#pragma unroll
        for (int c = 0; c < 37; ++c)
            tot[c] = part[0][c] + part[1][c] + part[2][c] + part[3][c];
        double s = 0.0;
#pragma unroll
        for (int c = 0; c < NH3; ++c)
            s += tot[NH3 + c] * tot[c];             // colsum(W_user) . ysum == sum(S)
        out[(size_t)NB * NH3] = (float)(-(s - tot[36]));
    }
}

extern "C" void kernel_launch(void* const* d_in, const int* in_sizes, int n_in,
                              void* d_out, int out_size, void* d_ws, size_t ws_size,
                              hipStream_t stream) {
    const float* x  = (const float*)d_in[0];
    const float* y  = (const float*)d_in[1];
    const float* W1 = (const float*)d_in[2];
    const float* b1 = (const float*)d_in[3];
    const float* W2 = (const float*)d_in[4];
    const float* b2 = (const float*)d_in[5];
    const float* W3 = (const float*)d_in[6];
    const float* b3 = (const float*)d_in[7];
    // d_in[8] (cases) folded into the factorized logsumexp.
    float* out = (float*)d_out;
    float* ws  = (float*)d_ws;

    fused_main<<<dim3(NBLK), dim3(TPB), 0, stream>>>(x, y, W1, b1, W2, b2, W3, b3, out, ws);
    finalize_loss<<<dim3(1), dim3(256), 0, stream>>>(ws, out);
}